// Round 2
// baseline (547.669 us; speedup 1.0000x reference)
//
#include <hip/hip_runtime.h>
#include <stdint.h>

#define K_DIM 4096
#define N_DIM 4096
#define M_DIM 8192

// GEMM tile geometry (3-buffer counted-vmcnt pipeline)
#define BM 256
#define BN 128
#define BK 64
#define NT (K_DIM / BK)          // 64 K-tiles

typedef __bf16 bf16x8 __attribute__((ext_vector_type(8)));
typedef _Float16 f16x8 __attribute__((ext_vector_type(8)));
typedef unsigned short u16x8 __attribute__((ext_vector_type(8)));
typedef float floatx4 __attribute__((ext_vector_type(4)));

// Device-global scratch (module .bss). Stored dtype-neutral as u16:
//   g_Bt: fp16 when x is fp16/f32 (f16-MFMA path), bf16 when x is bf16.
//   g_X : fp16 conversion of x, only used when x is f32 (mode 1).
__device__ __attribute__((aligned(256))) unsigned short g_Bt[(size_t)N_DIM * K_DIM];
__device__ __attribute__((aligned(256))) unsigned short g_X [(size_t)M_DIM * K_DIM];
__device__ int g_flags[2]; // [0]: x dtype 0=bf16 1=f32 2=fp16 ; [1]: perm is candB

__device__ __forceinline__ void global_to_lds16(const void* g, void* l) {
    // width=16 async global->LDS; LDS dest = wave-uniform base + lane*16 (linear!)
    __builtin_amdgcn_global_load_lds(
        (const __attribute__((address_space(1))) uint32_t*)g,
        (__attribute__((address_space(3))) uint32_t*)l,
        16, 0, 0);
}

#define LDS_FENCE() asm volatile("" ::: "memory")

// ---------------- probe: classify dtypes / disambiguate same-size inputs ----------------
__global__ void probe_kernel(const void* xraw, const int* candA, const int* candB) {
    __shared__ int s_insane, s_small, s_badA, s_badB;
    if (threadIdx.x == 0) { s_insane = 0; s_small = 0; s_badA = 0; s_badB = 0; }
    __syncthreads();
    const uint16_t* xw = (const uint16_t*)xraw;
    int insane = 0, small = 0;
    for (int i = threadIdx.x; i < 8192; i += 256) {
        uint16_t a = (uint16_t)(xw[2 * i] & 0x7FFF);   // EVEN 16-bit words of x
        if (a >= 0x4300) insane++;                     // f32 mantissa junk ~48%; bf16 N(0,1) ~0
        if (a > 0 && a < 0x3000) small++;              // fp16 N(0,1) ~10%; bf16 ~0
    }
    int badA = 0, badB = 0;
    for (int i = threadIdx.x; i < 4096; i += 256) {
        if ((unsigned)candA[i] >= 4096u) badA++;       // permutation: all in [0,4096)
        if ((unsigned)candB[i] >= 4096u) badB++;
    }
    atomicAdd(&s_insane, insane); atomicAdd(&s_small, small);
    atomicAdd(&s_badA, badA);     atomicAdd(&s_badB, badB);
    __syncthreads();
    if (threadIdx.x == 0) {
        int mode = 0;
        if (s_insane > 32) mode = 1;          // float32
        else if (s_small > 100) mode = 2;     // float16
        g_flags[0] = mode;
        g_flags[1] = (s_badA > 0 && s_badB == 0) ? 1 : 0;
    }
}

// ---------------- normalize x -> fp16 g_X (ONLY when x is f32; fp16/bf16 read raw) ----------------
__global__ void __launch_bounds__(256) convert_x_kernel(const void* xraw) {
    if (g_flags[0] != 1) return;              // data-dependent, deterministic per call
    const size_t nchunk = (size_t)M_DIM * K_DIM / 8;
    const float* xf = (const float*)xraw;
    for (size_t c = (size_t)blockIdx.x * 256 + threadIdx.x; c < nchunk;
         c += (size_t)gridDim.x * 256) {
        size_t base = c * 8;
        float4 v0 = *(const float4*)(xf + base);
        float4 v1 = *(const float4*)(xf + base + 4);
        u16x8 o;
        _Float16 h;
        h = (_Float16)v0.x; o[0] = __builtin_bit_cast(unsigned short, h);
        h = (_Float16)v0.y; o[1] = __builtin_bit_cast(unsigned short, h);
        h = (_Float16)v0.z; o[2] = __builtin_bit_cast(unsigned short, h);
        h = (_Float16)v0.w; o[3] = __builtin_bit_cast(unsigned short, h);
        h = (_Float16)v1.x; o[4] = __builtin_bit_cast(unsigned short, h);
        h = (_Float16)v1.y; o[5] = __builtin_bit_cast(unsigned short, h);
        h = (_Float16)v1.z; o[6] = __builtin_bit_cast(unsigned short, h);
        h = (_Float16)v1.w; o[7] = __builtin_bit_cast(unsigned short, h);
        *(u16x8*)(g_X + base) = o;
    }
}

// ---------------- dequant + K-perm folded into weights ----------------
// g_Bt[n][j] = (w4(k,n)-8) * (s4(g,n)+1)^2 * (smax[g]/256),  k = q_invperm[j]
// Round-1 post-mortem: read-coalesced mapping made WRITES scattered (16B stores
// 8KB apart -> ~200us of partial-line HBM writes). Fix: LDS transpose tile.
//   Phase 1 (read-optimal): 16 lanes = 16 contiguous n, same j-pack -> one 64B
//     q_weight line per group per nibble. Results -> LDS [16 n][136 j-pad].
//   Phase 2 (write-optimal): 16 lanes = 16 contiguous j-packs of one n row ->
//     256B contiguous store. Pad 136 balances banks (conflict-free b128).
// Output dtype: fp16 when mode!=0 (f16-MFMA path), bf16 when mode==0.
__global__ void __launch_bounds__(256) dequant_perm_kernel(
    const int* __restrict__ q_weight,        // [K/8][N]
    const int* __restrict__ q_scale,         // [G][N/8]
    const void* __restrict__ qsm_raw,        // [G] (dtype per flag)
    const int* __restrict__ candA, const int* __restrict__ candB)
{
    __shared__ __attribute__((aligned(16))) unsigned short lds[16 * 136];

    const int mode = g_flags[0];
    const int* q_invperm = g_flags[1] ? candB : candA;

    const int n_l  = threadIdx.x & 15;
    const int jp_l = threadIdx.x >> 4;                 // 0..15
    const int n  = blockIdx.x * 16 + n_l;              // 16 contiguous n per group
    const int j0 = (blockIdx.y * 16 + jp_l) << 3;      // j-pack (8 outputs)

    int4 ip0 = *(const int4*)(q_invperm + j0);         // broadcast within 16-lane group
    int4 ip1 = *(const int4*)(q_invperm + j0 + 4);
    int ks[8] = {ip0.x, ip0.y, ip0.z, ip0.w, ip1.x, ip1.y, ip1.z, ip1.w};

    const int nshift = (n & 7) << 2;
    const int scol = n >> 3;

    u16x8 ov;
#pragma unroll
    for (int u = 0; u < 8; ++u) {
        int k = ks[u] & (K_DIM - 1);               // defensive clamp
        int w4 = (q_weight[(size_t)(k >> 3) * N_DIM + n] >> ((k & 7) << 2)) & 0xF;
        int g = k >> 7;
        int s4 = (q_scale[g * (N_DIM / 8) + scol] >> nshift) & 0xF;
        float smax;
        if (mode == 1)      smax = ((const float*)qsm_raw)[g];
        else if (mode == 2) smax = (float)((const _Float16*)qsm_raw)[g];
        else                smax = (float)((const __bf16*)qsm_raw)[g];
        float sp1 = (float)(s4 + 1);
        float w = (float)(w4 - 8) * (sp1 * sp1 * smax * (1.0f / 256.0f));
        if (mode != 0) { _Float16 h = (_Float16)w; ov[u] = __builtin_bit_cast(unsigned short, h); }
        else           { __bf16   b = (__bf16)w;   ov[u] = __builtin_bit_cast(unsigned short, b); }
    }
    // LDS stage: row n_l (pitch 136 elems = 272B -> start-bank 4*(n_l+jp_l)%32, balanced)
    *(u16x8*)&lds[n_l * 136 + jp_l * 8] = ov;
    __syncthreads();

    // write-optimal remap: 16 lanes sweep one n row's 128 j = 256B contiguous
    const int row = threadIdx.x >> 4;                  // n_l of the row we drain
    const int c16 = threadIdx.x & 15;                  // j-pack within row
    u16x8 t = *(const u16x8*)&lds[row * 136 + c16 * 8];
    *(u16x8*)(g_Bt + (size_t)(blockIdx.x * 16 + row) * K_DIM
              + (size_t)blockIdx.y * 128 + c16 * 8) = t;
}

// ---------------- GEMM: C = X * g_Bt^T + bias ----------------
// 256x128 tile, BK=64, 8 waves (4M x 2N of 64x64), 3-deep LDS pipeline:
// stage tile t+2 while computing tile t, steady-state s_waitcnt vmcnt(6)
// (never 0 in main loop). LDS XOR-swizzle via linear gload_lds dest +
// inverse-swizzled GLOBAL source + swizzled ds_read (rule 21, verified:
// SQ_LDS_BANK_CONFLICT 1.0e8 -> 0). setprio(1) around MFMA cluster (T5).
// Templated on element type: F16=true -> mfma f16 (x fp16/f32 path, no
// x-conversion for fp16), F16=false -> mfma bf16. Device-side mode guard.
template <bool F16>
__global__ void __launch_bounds__(512, 2) gemm_bt_kernel(
    const void* __restrict__ xraw,
    const void* __restrict__ bias_candA, const void* __restrict__ bias_candB,
    void* __restrict__ outraw)
{
    const int mode = g_flags[0];
    if (F16 != (mode != 0)) return;            // wrong instantiation: exit (~us)

    // A: [3][256][64] = 96 KiB ; B: [3][128][64] = 48 KiB ; total 144 KiB
    __shared__ __attribute__((aligned(128))) unsigned short sm[3 * BM * BK + 3 * BN * BK];
    const int SB = 3 * BM * BK;                 // element base of B region

    const void* bias_raw = g_flags[1] ? bias_candA : bias_candB; // perm==B -> bias==A
    const unsigned short* __restrict__ Xp =
        (mode == 1) ? g_X : (const unsigned short*)xraw;
    const unsigned short* __restrict__ Bt = g_Bt;

    const int tid  = threadIdx.x;
    const int wave = tid >> 6;
    const int lane = tid & 63;

    // XCD-aware bijective swizzle: nwg = 32*32 = 1024, divisible by 8
    const int orig = blockIdx.y * 32 + blockIdx.x;
    const int swz  = (orig & 7) * (1024 >> 3) + (orig >> 3);
    const int bn0  = (swz & 31) * BN;
    const int bm0  = (swz >> 5) * BM;

    // ---- staging geometry (per gload: one wave covers 8 rows x 64 k = 1 KiB) ----
    const int lrow8 = lane >> 3;                        // row within 8-row chunk
    const int ksw   = ((lane & 7) ^ lrow8) << 3;        // inverse-swizzled global k offs (elems)
    const size_t aoff = (size_t)(bm0 + wave * 32 + lrow8) * K_DIM + ksw;
    const size_t boff = (size_t)(bn0 + wave * 16 + lrow8) * K_DIM + ksw;
    const int aldsb = (wave * 4) * 512;                 // wave's A chunk-0 base (elems)
    const int bldsb = (wave * 2) * 512;                 // wave's B chunk-0 base (elems)

    // ---- fragment geometry ----
    const int wm   = (wave >> 1) << 6;                  // 0,64,128,192 (M)
    const int wn   = (wave & 1) << 6;                   // 0,64 (N)
    const int frow = lane & 15;
    const int fk   = (lane >> 4) << 3;                  // 0,8,16,24
    const int ksw8 = (lane & 7) << 3;                   // read-side swizzle XOR (elems)

    floatx4 acc[4][4] = {};

    // ---- prologue: stage tiles 0,1 into buffers 0,1 (12 loads), wait oldest 6 ----
#pragma unroll
    for (int tt = 0; tt < 2; ++tt) {
#pragma unroll
        for (int c = 0; c < 4; ++c)
            global_to_lds16(Xp + aoff + (size_t)c * (8 * K_DIM) + tt * BK,
                            &sm[tt * (BM * BK) + aldsb + c * 512]);
#pragma unroll
        for (int c = 0; c < 2; ++c)
            global_to_lds16(Bt + boff + (size_t)c * (8 * K_DIM) + tt * BK,
                            &sm[SB + tt * (BN * BK) + bldsb + c * 512]);
    }
    asm volatile("s_waitcnt vmcnt(6)" ::: "memory");    // tile0 resident; tile1 in flight
    LDS_FENCE();
    __builtin_amdgcn_s_barrier();
    LDS_FENCE();

    int cur = 0;
#pragma unroll 1
    for (int t = 0; t < NT; ++t) {
        int nb = cur + 2; if (nb >= 3) nb -= 3;
        const int curA = cur * (BM * BK);
        const int curB = SB + cur * (BN * BK);
        const bool stage = (t + 2 < NT);
        const int kt2 = (t + 2) * BK;

#pragma unroll
        for (int ks = 0; ks < 2; ++ks) {
            // phase: 8 swizzled ds_read_b128  ||  3 global_load_lds  ||  16 MFMA
            u16x8 a[4], b[4];
            const int kb = (ks * 32 + fk) ^ ksw8;
#pragma unroll
            for (int i = 0; i < 4; ++i)
                a[i] = *(const u16x8*)&sm[curA + (wm + i * 16 + frow) * 64 + kb];
#pragma unroll
            for (int j = 0; j < 4; ++j)
                b[j] = *(const u16x8*)&sm[curB + (wn + j * 16 + frow) * 64 + kb];

            if (stage) {
                if (ks == 0) {
#pragma unroll
                    for (int c = 0; c < 3; ++c)
                        global_to_lds16(Xp + aoff + (size_t)c * (8 * K_DIM) + kt2,
                                        &sm[nb * (BM * BK) + aldsb + c * 512]);
                } else {
                    global_to_lds16(Xp + aoff + (size_t)3 * (8 * K_DIM) + kt2,
                                    &sm[nb * (BM * BK) + aldsb + 3 * 512]);
#pragma unroll
                    for (int c = 0; c < 2; ++c)
                        global_to_lds16(Bt + boff + (size_t)c * (8 * K_DIM) + kt2,
                                        &sm[SB + nb * (BN * BK) + bldsb + c * 512]);
                }
            }
            if (ks == 1) {
                // counted wait: tile t+1's 6 loads done; tile t+2's 6 stay in flight
                if (stage) asm volatile("s_waitcnt vmcnt(6)" ::: "memory");
                else       asm volatile("s_waitcnt vmcnt(0)" ::: "memory"); // drain tail
            }
            LDS_FENCE();
            __builtin_amdgcn_s_barrier();
            LDS_FENCE();

            __builtin_amdgcn_s_setprio(1);
#pragma unroll
            for (int i = 0; i < 4; ++i)
#pragma unroll
                for (int j = 0; j < 4; ++j) {
                    if constexpr (F16)
                        acc[i][j] = __builtin_amdgcn_mfma_f32_16x16x32_f16(
                            __builtin_bit_cast(f16x8, a[i]),
                            __builtin_bit_cast(f16x8, b[j]), acc[i][j], 0, 0, 0);
                    else
                        acc[i][j] = __builtin_amdgcn_mfma_f32_16x16x32_bf16(
                            __builtin_bit_cast(bf16x8, a[i]),
                            __builtin_bit_cast(bf16x8, b[j]), acc[i][j], 0, 0, 0);
                }
            __builtin_amdgcn_s_setprio(0);

            LDS_FENCE();
            __builtin_amdgcn_s_barrier();
            LDS_FENCE();
        }
        cur = cur + 1; if (cur >= 3) cur = 0;
    }

    // Epilogue: C/D layout col=lane&15, row=(lane>>4)*4+reg  [m89-verified]
    const int ccol = lane & 15;
    const int crow = (lane >> 4) << 2;
#pragma unroll
    for (int j = 0; j < 4; ++j) {
        const int col = bn0 + wn + j * 16 + ccol;
        float bv;
        if (mode == 1)      bv = ((const float*)bias_raw)[col];
        else if (mode == 2) bv = (float)((const _Float16*)bias_raw)[col];
        else                bv = (float)((const __bf16*)bias_raw)[col];
#pragma unroll
        for (int i = 0; i < 4; ++i) {
            const int row = bm0 + wm + i * 16 + crow;
#pragma unroll
            for (int r = 0; r < 4; ++r) {
                float v = acc[i][j][r] + bv;
                size_t idx = (size_t)(row + r) * N_DIM + col;
                if (mode == 1)      ((float*)outraw)[idx] = v;
                else if (mode == 2) ((_Float16*)outraw)[idx] = (_Float16)v;
                else                ((__bf16*)outraw)[idx] = (__bf16)v;
            }
        }
    }
}

extern "C" void kernel_launch(void* const* d_in, const int* in_sizes, int n_in,
                              void* d_out, int out_size, void* d_ws, size_t ws_size,
                              hipStream_t stream) {
    // Map inputs by element count (round-5 lesson: d_in is NOT in dict order).
    int idx_x = 0, idx_qw = 1, idx_qs = 2, idx_qsm = 3, idx_a = -1, idx_b = -1;
    for (int i = 0; i < n_in; ++i) {
        switch (in_sizes[i]) {
            case 33554432: idx_x = i; break;                       // x [8192][4096]
            case 2097152:  idx_qw = i; break;                      // q_weight [512][4096]
            case 16384:    idx_qs = i; break;                      // q_scale [32][512]
            case 32:       idx_qsm = i; break;                     // q_scale_max [32]
            case 4096:     (idx_a < 0 ? idx_a : idx_b) = i; break; // q_invperm / bias
            default: break;
        }
    }
    if (idx_a < 0) idx_a = 4;
    if (idx_b < 0) idx_b = 5;

    const void* xraw  = d_in[idx_x];
    const int*  qw    = (const int*)d_in[idx_qw];
    const int*  qs    = (const int*)d_in[idx_qs];
    const void* qsm   = d_in[idx_qsm];
    const int*  candA = (const int*)d_in[idx_a];
    const int*  candB = (const int*)d_in[idx_b];

    probe_kernel<<<1, 256, 0, stream>>>(xraw, candA, candB);
    convert_x_kernel<<<2048, 256, 0, stream>>>(xraw);   // f32 inputs only; exits otherwise
    dim3 dqg(N_DIM / 16, (K_DIM / 8) / 16);             // 16 n x 128 j tile per block
    dequant_perm_kernel<<<dqg, 256, 0, stream>>>(qw, qs, qsm, candA, candB);
    dim3 grid(N_DIM / BN, M_DIM / BM);                  // (32, 32)
    gemm_bt_kernel<true ><<<grid, 512, 0, stream>>>(xraw, d_in[idx_a], d_in[idx_b], d_out);
    gemm_bt_kernel<false><<<grid, 512, 0, stream>>>(xraw, d_in[idx_a], d_in[idx_b], d_out);
}

// Round 3
// 479.933 us; speedup vs baseline: 1.1411x; 1.1411x over previous
//
#include <hip/hip_runtime.h>
#include <stdint.h>

#define K_DIM 4096
#define N_DIM 4096
#define M_DIM 8192

// GEMM tile geometry: 256x256 tile, BK=64, 2-buffer half-tile pipeline
#define BM 256
#define BN 256
#define BK 64
#define NT (K_DIM / BK)          // 64 K-tiles

typedef __bf16 bf16x8 __attribute__((ext_vector_type(8)));
typedef _Float16 f16x8 __attribute__((ext_vector_type(8)));
typedef unsigned short u16x8 __attribute__((ext_vector_type(8)));
typedef float floatx4 __attribute__((ext_vector_type(4)));

// Device-global scratch (module .bss). Stored dtype-neutral as u16:
//   g_Bt: fp16 when x is fp16/f32 (f16-MFMA path), bf16 when x is bf16.
//   g_X : fp16 conversion of x, only used when x is f32 (mode 1).
__device__ __attribute__((aligned(256))) unsigned short g_Bt[(size_t)N_DIM * K_DIM];
__device__ __attribute__((aligned(256))) unsigned short g_X [(size_t)M_DIM * K_DIM];
__device__ int g_flags[2];  // [0]: x dtype 0=bf16 1=f32 2=fp16 ; [1]: perm is candB
__device__ int g_counts[4]; // probe partials; zeroed at module load, re-zeroed by finalize

__device__ __forceinline__ void global_to_lds16(const void* g, void* l) {
    // width=16 async global->LDS; LDS dest = wave-uniform base + lane*16 (linear!)
    __builtin_amdgcn_global_load_lds(
        (const __attribute__((address_space(1))) uint32_t*)g,
        (__attribute__((address_space(3))) uint32_t*)l,
        16, 0, 0);
}

#define LDS_FENCE() asm volatile("" ::: "memory")
#define BARRIER() do { LDS_FENCE(); __builtin_amdgcn_s_barrier(); LDS_FENCE(); } while (0)

// ---------------- probe (32 blocks, parallel) + finalize ----------------
__global__ void probe_kernel(const void* xraw, const int* candA, const int* candB) {
    __shared__ int s[4];
    if (threadIdx.x < 4) s[threadIdx.x] = 0;
    __syncthreads();
    const uint16_t* xw = (const uint16_t*)xraw;
    const int gidx = blockIdx.x * 256 + threadIdx.x;   // 8192 samples total
    int insane = 0, small = 0;
    {
        uint16_t a = (uint16_t)(xw[2 * gidx] & 0x7FFF); // EVEN 16-bit words of x
        if (a >= 0x4300) insane++;                      // f32 mantissa junk ~48%; bf16 ~0
        if (a > 0 && a < 0x3000) small++;               // fp16 N(0,1) ~10%; bf16 ~0
    }
    int badA = 0, badB = 0;
    if (gidx < 4096) {
        if ((unsigned)candA[gidx] >= 4096u) badA++;     // permutation: all in [0,4096)
        if ((unsigned)candB[gidx] >= 4096u) badB++;
    }
    atomicAdd(&s[0], insane); atomicAdd(&s[1], small);
    atomicAdd(&s[2], badA);   atomicAdd(&s[3], badB);
    __syncthreads();
    if (threadIdx.x < 4 && s[threadIdx.x] != 0) atomicAdd(&g_counts[threadIdx.x], s[threadIdx.x]);
}

__global__ void finalize_kernel() {
    int insane = g_counts[0], small = g_counts[1];
    int badA = g_counts[2], badB = g_counts[3];
    int mode = 0;
    if (insane > 32) mode = 1;            // float32
    else if (small > 100) mode = 2;       // float16
    g_flags[0] = mode;
    g_flags[1] = (badA > 0 && badB == 0) ? 1 : 0;
    g_counts[0] = g_counts[1] = g_counts[2] = g_counts[3] = 0;  // reset for next call
}

// ---------------- normalize x -> fp16 g_X (ONLY when x is f32) ----------------
__global__ void __launch_bounds__(256) convert_x_kernel(const void* xraw) {
    if (g_flags[0] != 1) return;
    const size_t nchunk = (size_t)M_DIM * K_DIM / 8;
    const float* xf = (const float*)xraw;
    for (size_t c = (size_t)blockIdx.x * 256 + threadIdx.x; c < nchunk;
         c += (size_t)gridDim.x * 256) {
        size_t base = c * 8;
        float4 v0 = *(const float4*)(xf + base);
        float4 v1 = *(const float4*)(xf + base + 4);
        u16x8 o;
        _Float16 h;
        h = (_Float16)v0.x; o[0] = __builtin_bit_cast(unsigned short, h);
        h = (_Float16)v0.y; o[1] = __builtin_bit_cast(unsigned short, h);
        h = (_Float16)v0.z; o[2] = __builtin_bit_cast(unsigned short, h);
        h = (_Float16)v0.w; o[3] = __builtin_bit_cast(unsigned short, h);
        h = (_Float16)v1.x; o[4] = __builtin_bit_cast(unsigned short, h);
        h = (_Float16)v1.y; o[5] = __builtin_bit_cast(unsigned short, h);
        h = (_Float16)v1.z; o[6] = __builtin_bit_cast(unsigned short, h);
        h = (_Float16)v1.w; o[7] = __builtin_bit_cast(unsigned short, h);
        *(u16x8*)(g_X + base) = o;
    }
}

// ---------------- dequant + K-perm folded into weights (r2 LDS-transpose version) ----------------
__global__ void __launch_bounds__(256) dequant_perm_kernel(
    const int* __restrict__ q_weight,        // [K/8][N]
    const int* __restrict__ q_scale,         // [G][N/8]
    const void* __restrict__ qsm_raw,        // [G] (dtype per flag)
    const int* __restrict__ candA, const int* __restrict__ candB)
{
    __shared__ __attribute__((aligned(16))) unsigned short lds[16 * 136];

    const int mode = g_flags[0];
    const int* q_invperm = g_flags[1] ? candB : candA;

    const int n_l  = threadIdx.x & 15;
    const int jp_l = threadIdx.x >> 4;
    const int n  = blockIdx.x * 16 + n_l;              // 16 contiguous n per group
    const int j0 = (blockIdx.y * 16 + jp_l) << 3;      // j-pack (8 outputs)

    int4 ip0 = *(const int4*)(q_invperm + j0);
    int4 ip1 = *(const int4*)(q_invperm + j0 + 4);
    int ks[8] = {ip0.x, ip0.y, ip0.z, ip0.w, ip1.x, ip1.y, ip1.z, ip1.w};

    const int nshift = (n & 7) << 2;
    const int scol = n >> 3;

    u16x8 ov;
#pragma unroll
    for (int u = 0; u < 8; ++u) {
        int k = ks[u] & (K_DIM - 1);
        int w4 = (q_weight[(size_t)(k >> 3) * N_DIM + n] >> ((k & 7) << 2)) & 0xF;
        int g = k >> 7;
        int s4 = (q_scale[g * (N_DIM / 8) + scol] >> nshift) & 0xF;
        float smax;
        if (mode == 1)      smax = ((const float*)qsm_raw)[g];
        else if (mode == 2) smax = (float)((const _Float16*)qsm_raw)[g];
        else                smax = (float)((const __bf16*)qsm_raw)[g];
        float sp1 = (float)(s4 + 1);
        float w = (float)(w4 - 8) * (sp1 * sp1 * smax * (1.0f / 256.0f));
        if (mode != 0) { _Float16 h = (_Float16)w; ov[u] = __builtin_bit_cast(unsigned short, h); }
        else           { __bf16   b = (__bf16)w;   ov[u] = __builtin_bit_cast(unsigned short, b); }
    }
    *(u16x8*)&lds[n_l * 136 + jp_l * 8] = ov;
    __syncthreads();

    const int row = threadIdx.x >> 4;
    const int c16 = threadIdx.x & 15;
    u16x8 t = *(const u16x8*)&lds[row * 136 + c16 * 8];
    *(u16x8*)(g_Bt + (size_t)(blockIdx.x * 16 + row) * K_DIM
              + (size_t)blockIdx.y * 128 + c16 * 8) = t;
}

// ---------------- GEMM: C = X * g_Bt^T + bias ----------------
// 256x256 tile, BK=64, 8 waves. 2-buffer HALF-TILE pipeline, 4 phases/tile:
//   wave stripes interleaved at 16 granularity (m = i*32+(w>>2)*16,
//   n = j*64+(w&3)*16) so EVERY wave consumes staged half-tiles progressively:
//     p0 needs A-half0+B-half0 | p1 +B-half1 | p2 +A-half1 | p3 nothing new.
//   Stage order for tile t+1: A0'@p0, B0'@p1, B1'@p2, A1'@p3 (2 gloads each).
//   Counted waits (never 0 in main loop): vmcnt(4) at p0/p1/p3 -> >=4 loads
//   always in flight. lgkmcnt(0) before each barrier publishes ds_reads so the
//   next tile's stages may overwrite the other buffer (race-checked).
// Same verified XOR-swizzle wiring as r1/r2 (bank conflicts measured 0).
template <bool F16>
__global__ void __launch_bounds__(512, 2) gemm_bt_kernel(
    const void* __restrict__ xraw,
    const void* __restrict__ bias_candA, const void* __restrict__ bias_candB,
    void* __restrict__ outraw)
{
    const int mode = g_flags[0];
    if (F16 != (mode != 0)) return;            // wrong instantiation: exit (~us)

    // A buf0 | A buf1 | B buf0 | B buf1, each [256][64] u16 = 32 KiB; total 128 KiB
    __shared__ __attribute__((aligned(128))) unsigned short sm[4 * 256 * 64];
    const int ASZ = 256 * 64;                  // 16384 elems per buffer
    const int SB  = 2 * ASZ;                   // B region base

    const void* bias_raw = g_flags[1] ? bias_candA : bias_candB; // perm==B -> bias==A
    const unsigned short* __restrict__ Xp =
        (mode == 1) ? g_X : (const unsigned short*)xraw;
    const unsigned short* __restrict__ Bt = g_Bt;

    const int tid  = threadIdx.x;
    const int wave = tid >> 6;
    const int lane = tid & 63;

    // grid 16 x 32 = 512 wgs; bijective XCD swizzle (512 % 8 == 0)
    const int orig = blockIdx.y * 16 + blockIdx.x;
    const int swz  = (orig & 7) * 64 + (orig >> 3);
    const int bn0  = (swz & 15) * BN;
    const int bm0  = (swz >> 4) * BM;

    // ---- staging geometry (per gload: wave covers 8 rows x 64 k = 1 KiB) ----
    const int lrow8 = lane >> 3;                        // row within 8-row chunk
    const int ksw   = ((lane & 7) ^ lrow8) << 3;        // inverse-swizzled global k (elems)
    const size_t aoff = (size_t)(bm0 + wave * 8 + lrow8) * K_DIM + ksw;
    const size_t boff = (size_t)(bn0 + wave * 8 + lrow8) * K_DIM + ksw;
    const int ldsw = (wave * 8) * 64;                   // wave's row offset in a chunk (elems)

    // ---- fragment geometry (interleaved 16-row stripes) ----
    const int w_m16 = (wave >> 2) << 4;                 // 0 or 16
    const int w_n16 = (wave & 3) << 4;                  // 0,16,32,48
    const int frow  = lane & 15;
    const int fk    = (lane >> 4) << 3;                 // 0,8,16,24
    const int ksw8  = (lane & 7) << 3;                  // read-side swizzle XOR (elems)

    floatx4 acc[8][4] = {};
    u16x8 a[4][2], b[4][2];

// stage one 64-row chunk (h = half, c = chunk-in-half) of tile at k-offset ktt
#define STAGE_A(bufbase, h, c, ktt) \
    global_to_lds16(Xp + aoff + (size_t)((h) * 128 + (c) * 64) * K_DIM + (ktt), \
                    &sm[(bufbase) + ((h) * 128 + (c) * 64) * 64 + ldsw])
#define STAGE_B(bufbase, h, c, ktt) \
    global_to_lds16(Bt + boff + (size_t)((h) * 128 + (c) * 64) * K_DIM + (ktt), \
                    &sm[SB + (bufbase) + ((h) * 128 + (c) * 64) * 64 + ldsw])

#define MFMA_PH(ibase, jbase) do { \
    __builtin_amdgcn_s_setprio(1); \
    _Pragma("unroll") \
    for (int ii = 0; ii < 4; ++ii) \
        _Pragma("unroll") \
        for (int jj = 0; jj < 2; ++jj) \
            _Pragma("unroll") \
            for (int kh = 0; kh < 2; ++kh) { \
                if constexpr (F16) \
                    acc[(ibase) + ii][(jbase) + jj] = __builtin_amdgcn_mfma_f32_16x16x32_f16( \
                        __builtin_bit_cast(f16x8, a[ii][kh]), \
                        __builtin_bit_cast(f16x8, b[(jbase) + jj][kh]), \
                        acc[(ibase) + ii][(jbase) + jj], 0, 0, 0); \
                else \
                    acc[(ibase) + ii][(jbase) + jj] = __builtin_amdgcn_mfma_f32_16x16x32_bf16( \
                        __builtin_bit_cast(bf16x8, a[ii][kh]), \
                        __builtin_bit_cast(bf16x8, b[(jbase) + jj][kh]), \
                        acc[(ibase) + ii][(jbase) + jj], 0, 0, 0); \
            } \
    __builtin_amdgcn_s_setprio(0); \
} while (0)

    // ---- prologue: stage tile 0 -> buf 0 in order A0,B0,B1,A1; wait oldest 4 ----
    STAGE_A(0, 0, 0, 0); STAGE_A(0, 0, 1, 0);
    STAGE_B(0, 0, 0, 0); STAGE_B(0, 0, 1, 0);
    STAGE_B(0, 1, 0, 0); STAGE_B(0, 1, 1, 0);
    STAGE_A(0, 1, 0, 0); STAGE_A(0, 1, 1, 0);
    asm volatile("s_waitcnt vmcnt(4)" ::: "memory");    // A0,B0 resident; B1,A1 in flight
    BARRIER();

    int cur = 0;
#pragma unroll 1
    for (int t = 0; t < NT; ++t) {
        const int nxt = cur ^ 1;
        const int curA = cur * ASZ;
        const int curB = cur * ASZ;                     // used with SB +
        const int nbA = nxt * ASZ;
        const int nbB = nxt * ASZ;
        const bool st = (t + 1 < NT);
        const int kt1 = (t + 1) * BK;

        // -------- phase 0: read a(mh0) + b(j0,1); stage A0'; need B1c next --------
#pragma unroll
        for (int ii = 0; ii < 4; ++ii)
#pragma unroll
            for (int kh = 0; kh < 2; ++kh)
                a[ii][kh] = *(const u16x8*)&sm[curA + (ii * 32 + w_m16 + frow) * 64
                                              + ((kh * 32 + fk) ^ ksw8)];
#pragma unroll
        for (int j = 0; j < 2; ++j)
#pragma unroll
            for (int kh = 0; kh < 2; ++kh)
                b[j][kh] = *(const u16x8*)&sm[SB + curB + (j * 64 + w_n16 + frow) * 64
                                              + ((kh * 32 + fk) ^ ksw8)];
        if (st) { STAGE_A(nbA, 0, 0, kt1); STAGE_A(nbA, 0, 1, kt1); }
        if (st) asm volatile("s_waitcnt vmcnt(4) lgkmcnt(0)" ::: "memory");
        else    asm volatile("s_waitcnt vmcnt(2) lgkmcnt(0)" ::: "memory");
        BARRIER();
        MFMA_PH(0, 0);

        // -------- phase 1: read b(j2,3); stage B0'; need A1c next --------
#pragma unroll
        for (int j = 2; j < 4; ++j)
#pragma unroll
            for (int kh = 0; kh < 2; ++kh)
                b[j][kh] = *(const u16x8*)&sm[SB + curB + (j * 64 + w_n16 + frow) * 64
                                              + ((kh * 32 + fk) ^ ksw8)];
        if (st) { STAGE_B(nbB, 0, 0, kt1); STAGE_B(nbB, 0, 1, kt1); }
        if (st) asm volatile("s_waitcnt vmcnt(4) lgkmcnt(0)" ::: "memory");
        else    asm volatile("s_waitcnt vmcnt(0) lgkmcnt(0)" ::: "memory");
        BARRIER();
        MFMA_PH(0, 2);

        // -------- phase 2: read a(mh1); stage B1'; nothing needed next --------
#pragma unroll
        for (int ii = 0; ii < 4; ++ii)
#pragma unroll
            for (int kh = 0; kh < 2; ++kh)
                a[ii][kh] = *(const u16x8*)&sm[curA + ((ii + 4) * 32 + w_m16 + frow) * 64
                                               + ((kh * 32 + fk) ^ ksw8)];
        if (st) { STAGE_B(nbB, 1, 0, kt1); STAGE_B(nbB, 1, 1, kt1); }
        asm volatile("s_waitcnt lgkmcnt(0)" ::: "memory");
        BARRIER();
        MFMA_PH(4, 2);

        // -------- phase 3: no reads; stage A1'; need A0',B0' for next p0 --------
        if (st) {
            STAGE_A(nbA, 1, 0, kt1); STAGE_A(nbA, 1, 1, kt1);
            asm volatile("s_waitcnt vmcnt(4)" ::: "memory");
        }
        BARRIER();
        MFMA_PH(4, 0);

        cur = nxt;
    }

    // Epilogue: C/D layout col=lane&15, row=(lane>>4)*4+reg  [m89-verified]
    const int ccol = lane & 15;
    const int crow = (lane >> 4) << 2;
#pragma unroll
    for (int j = 0; j < 4; ++j) {
        const int col = bn0 + j * 64 + w_n16 + ccol;
        float bv;
        if (mode == 1)      bv = ((const float*)bias_raw)[col];
        else if (mode == 2) bv = (float)((const _Float16*)bias_raw)[col];
        else                bv = (float)((const __bf16*)bias_raw)[col];
#pragma unroll
        for (int i = 0; i < 8; ++i) {
            const int row = bm0 + i * 32 + w_m16 + crow;
#pragma unroll
            for (int r = 0; r < 4; ++r) {
                float v = acc[i][j][r] + bv;
                size_t idx = (size_t)(row + r) * N_DIM + col;
                if (mode == 1)      ((float*)outraw)[idx] = v;
                else if (mode == 2) ((_Float16*)outraw)[idx] = (_Float16)v;
                else                ((__bf16*)outraw)[idx] = (__bf16)v;
            }
        }
    }
#undef STAGE_A
#undef STAGE_B
#undef MFMA_PH
}

extern "C" void kernel_launch(void* const* d_in, const int* in_sizes, int n_in,
                              void* d_out, int out_size, void* d_ws, size_t ws_size,
                              hipStream_t stream) {
    // Map inputs by element count (d_in is NOT in dict order).
    int idx_x = 0, idx_qw = 1, idx_qs = 2, idx_qsm = 3, idx_a = -1, idx_b = -1;
    for (int i = 0; i < n_in; ++i) {
        switch (in_sizes[i]) {
            case 33554432: idx_x = i; break;                       // x [8192][4096]
            case 2097152:  idx_qw = i; break;                      // q_weight [512][4096]
            case 16384:    idx_qs = i; break;                      // q_scale [32][512]
            case 32:       idx_qsm = i; break;                     // q_scale_max [32]
            case 4096:     (idx_a < 0 ? idx_a : idx_b) = i; break; // q_invperm / bias
            default: break;
        }
    }
    if (idx_a < 0) idx_a = 4;
    if (idx_b < 0) idx_b = 5;

    const void* xraw  = d_in[idx_x];
    const int*  qw    = (const int*)d_in[idx_qw];
    const int*  qs    = (const int*)d_in[idx_qs];
    const void* qsm   = d_in[idx_qsm];
    const int*  candA = (const int*)d_in[idx_a];
    const int*  candB = (const int*)d_in[idx_b];

    probe_kernel<<<32, 256, 0, stream>>>(xraw, candA, candB);
    finalize_kernel<<<1, 1, 0, stream>>>();
    convert_x_kernel<<<2048, 256, 0, stream>>>(xraw);   // f32 inputs only; exits otherwise
    dim3 dqg(N_DIM / 16, (K_DIM / 8) / 16);             // 16 n x 128 j tile per block
    dequant_perm_kernel<<<dqg, 256, 0, stream>>>(qw, qs, qsm, candA, candB);
    dim3 grid(N_DIM / BN, M_DIM / BM);                  // (16, 32)
    gemm_bt_kernel<true ><<<grid, 512, 0, stream>>>(xraw, d_in[idx_a], d_in[idx_b], d_out);
    gemm_bt_kernel<false><<<grid, 512, 0, stream>>>(xraw, d_in[idx_a], d_in[idx_b], d_out);
}